// Round 1
// baseline (214.139 us; speedup 1.0000x reference)
//
#include <hip/hip_runtime.h>

// Problem constants (from reference): S=7, B=2, C=20, N=30, batch=16384
#define NCH 30
#define RANK_LIMIT 49          // S*S
#define L_COORD 5.0f
#define L_NOOBJ 0.5f

// ---------------------------------------------------------------------------
// Kernel 1: no-object confidence loss over all M rows.
// Each thread handles one row: loads p[4],p[9],t[4],t[9]; rows are 120B so
// the needed channels straddle every 128B line anyway -> full-array traffic
// is the floor; scalar loads keep instruction count minimal (4 loads/row).
// Block-reduce then one atomicAdd per block into ws[0].
// ---------------------------------------------------------------------------
__global__ __launch_bounds__(256) void noobj_kernel(const float* __restrict__ p,
                                                    const float* __restrict__ t,
                                                    float* __restrict__ ws, int M) {
    int row = blockIdx.x * blockDim.x + threadIdx.x;
    float acc = 0.0f;
    if (row < M) {
        int base = row * NCH;
        float t4 = t[base + 4];
        float t9 = t[base + 9];
        float p4 = p[base + 4];
        float p9 = p[base + 9];
        if (!(t4 > 0.0f)) {   // noobj cell
            float d0 = p4 - t4;
            float d1 = p9 - t9;
            acc = d0 * d0 + d1 * d1;
        }
    }
    // wave (64-lane) reduction
    #pragma unroll
    for (int off = 32; off > 0; off >>= 1)
        acc += __shfl_down(acc, off, 64);
    __shared__ float s[4];
    int lane = threadIdx.x & 63;
    int wid  = threadIdx.x >> 6;
    if (lane == 0) s[wid] = acc;
    __syncthreads();
    if (threadIdx.x == 0) {
        atomicAdd(ws, s[0] + s[1] + s[2] + s[3]);
    }
}

// ---------------------------------------------------------------------------
// Per-row "selected" bbox loss — faithful port of the reference including its
// bugs: x2y2 built from the already-transformed xy; lambda_coord only on the
// x / sqrt(w) terms; selected loss sums l1+l2+l3+IoU; argmax keeps first max.
// ---------------------------------------------------------------------------
__device__ inline float sel_loss(const float* __restrict__ p,
                                 const float* __restrict__ t, int row) {
    const float invS = 1.0f / 7.0f;
    int b0 = row * NCH;
    float tot0 = 0.f, tot1 = 0.f, iou0 = 0.f, iou1 = 0.f;
    #pragma unroll
    for (int j = 0; j < 2; ++j) {
        int o = b0 + 5 * j;
        float px = p[o + 0], py = p[o + 1], pw = p[o + 2], ph = p[o + 3], pc = p[o + 4];
        float tx = t[o + 0], ty = t[o + 1], tw = t[o + 2], th = t[o + 3], tc = t[o + 4];
        // transform (bug-preserving): x2y2 uses the NEW xy
        float pxy0 = px * invS - 0.5f * pw;
        float pxy1 = py * invS - 0.5f * ph;
        float p2x  = pxy0 * invS + 0.5f * pw;
        float p2y  = pxy1 * invS + 0.5f * ph;
        float txy0 = tx * invS - 0.5f * tw;
        float txy1 = ty * invS - 0.5f * th;
        float t2x  = txy0 * invS + 0.5f * tw;
        float t2y  = txy1 * invS + 0.5f * th;
        // l1: lambda_coord only on x
        float d0 = txy0 - pxy0, d1 = txy1 - pxy1;
        float l1 = L_COORD * d0 * d0 + d1 * d1;
        // l2: lambda_coord only on sqrt(x2)
        float s0 = sqrtf(t2x) - sqrtf(p2x);
        float s1 = sqrtf(t2y) - sqrtf(p2y);
        float l2 = L_COORD * s0 * s0 + s1 * s1;
        float dc = tc - pc;
        float l3 = dc * dc;
        // IoU of pred box j vs target box j
        float ltx = fmaxf(pxy0, txy0), lty = fmaxf(pxy1, txy1);
        float rbx = fminf(p2x, t2x),   rby = fminf(p2y, t2y);
        float wx  = fmaxf(rbx - ltx, 0.0f);
        float wy  = fmaxf(rby - lty, 0.0f);
        float inter  = wx * wy;
        float area_p = (p2x - pxy0) * (p2y - pxy1);
        float area_t = (t2x - txy0) * (t2y - txy1);
        float io = inter / (area_p + area_t - inter);
        float tt = l1 + l2 + l3 + io;
        if (j == 0) { iou0 = io; tot0 = tt; }
        else        { iou1 = io; tot1 = tt; }
    }
    // jnp.argmax picks the FIRST max: box 1 only if strictly greater
    return (iou1 > iou0) ? tot1 : tot0;
}

// ---------------------------------------------------------------------------
// Kernel 2: ordered scan for the bbox loss. Single 256-thread block walks row
// chunks in order, ballot-scans obj flags for exact global ranks, accumulates
// sel_loss for obj rows with rank < 49, stops once 49 objects are consumed
// (expected after ~1 chunk at 25% obj density). Finally combines with the
// noobj accumulator and writes the scalar output.
// ---------------------------------------------------------------------------
__global__ __launch_bounds__(256) void bbox_kernel(const float* __restrict__ p,
                                                   const float* __restrict__ t,
                                                   const float* __restrict__ ws,
                                                   float* __restrict__ out, int M) {
    __shared__ int   s_wcnt[4];
    __shared__ int   s_base;
    __shared__ float s_part[4];
    if (threadIdx.x == 0) s_base = 0;
    __syncthreads();

    float local = 0.0f;
    for (int start = 0; start < M; start += 256) {
        int row = start + (int)threadIdx.x;
        bool obj = false;
        if (row < M) obj = t[row * NCH + 4] > 0.0f;

        unsigned long long mask = __ballot(obj);
        int lane = threadIdx.x & 63;
        int wid  = threadIdx.x >> 6;
        if (lane == 0) s_wcnt[wid] = __popcll(mask);
        __syncthreads();

        int base = s_base;                       // snapshot before update
        int off = 0;
        for (int w = 0; w < wid; ++w) off += s_wcnt[w];
        int rank = base + off + __popcll(mask & ((1ULL << lane) - 1ULL));
        if (obj && rank < RANK_LIMIT) local += sel_loss(p, t, row);
        __syncthreads();

        if (threadIdx.x == 0)
            s_base = base + s_wcnt[0] + s_wcnt[1] + s_wcnt[2] + s_wcnt[3];
        __syncthreads();
        if (s_base >= RANK_LIMIT) break;        // uniform exit
    }

    // block reduce local
    #pragma unroll
    for (int o = 32; o > 0; o >>= 1)
        local += __shfl_down(local, o, 64);
    int lane = threadIdx.x & 63;
    int wid  = threadIdx.x >> 6;
    if (lane == 0) s_part[wid] = local;
    __syncthreads();
    if (threadIdx.x == 0) {
        float bbox = s_part[0] + s_part[1] + s_part[2] + s_part[3];
        out[0] = bbox + L_NOOBJ * ws[0];
    }
}

extern "C" void kernel_launch(void* const* d_in, const int* in_sizes, int n_in,
                              void* d_out, int out_size, void* d_ws, size_t ws_size,
                              hipStream_t stream) {
    const float* pred = (const float*)d_in[0];
    const float* targ = (const float*)d_in[1];
    float* out = (float*)d_out;
    float* acc = (float*)d_ws;

    int M = in_sizes[0] / NCH;   // 16384*49 = 802816 rows

    // ws is re-poisoned to 0xAA before every call — zero the accumulator.
    hipMemsetAsync(d_ws, 0, 16, stream);

    int blocks = (M + 255) / 256;
    noobj_kernel<<<blocks, 256, 0, stream>>>(pred, targ, acc, M);
    bbox_kernel<<<1, 256, 0, stream>>>(pred, targ, acc, out, M);
}